// Round 3
// baseline (330.900 us; speedup 1.0000x reference)
//
#include <hip/hip_runtime.h>
#include <hip/hip_bf16.h>
#include <cstdint>

#define TOKENS 8192
#define DIN 1024
#define DOUT 1024
#define NE 8

typedef __bf16 bf16;
typedef __attribute__((ext_vector_type(8))) __bf16 bf16x8;
typedef __attribute__((ext_vector_type(4))) float floatx4;
typedef __attribute__((ext_vector_type(2))) float floatx2;

// async global->LDS, 16B per lane. LDS dest must be wave-uniform base + lane*16.
__device__ __forceinline__ void async16(const void* gptr, void* lptr) {
  __builtin_amdgcn_global_load_lds(
      (const __attribute__((address_space(1))) void*)gptr,
      (__attribute__((address_space(3))) void*)lptr,
      16, 0, 0);
}

// ---------------------------------------------------------------------------
// Fused prep: blocks [0,2048) = gate softmax + x->bf16; blocks [2048,4096) =
// W[e][i][o] fp32 -> Wt[e][o][i] bf16 transpose. One dispatch saves a launch
// and lets the two phases overlap on different CUs.
// ---------------------------------------------------------------------------
__global__ __launch_bounds__(256) void prep_kernel(
    const float* __restrict__ x, const float* __restrict__ gw,
    const float* __restrict__ gb, float* __restrict__ g,
    bf16* __restrict__ xb, const float* __restrict__ w,
    bf16* __restrict__ wt) {
  __shared__ float tile[64][65];  // used by transpose half only

  if (blockIdx.x < 2048) {
    // ---- gate + x conversion: one wave per token ----
    const int lane = threadIdx.x & 63;
    const int wave = threadIdx.x >> 6;
    const int t = blockIdx.x * 4 + wave;
    const float* xr = x + (size_t)t * DIN;
    bf16* xbr = xb + (size_t)t * DIN;

    float acc[NE];
#pragma unroll
    for (int e = 0; e < NE; ++e) acc[e] = 0.f;

#pragma unroll
    for (int it = 0; it < 8; ++it) {
      const int i = it * 128 + lane * 2;  // rows i, i+1 (gw loads 64B/lane)
      const floatx2 xv = *(const floatx2*)(xr + i);
      union { bf16 b[2]; uint32_t u; } cv;
      cv.b[0] = (bf16)xv[0]; cv.b[1] = (bf16)xv[1];
      *(uint32_t*)(xbr + i) = cv.u;
      const floatx4 w00 = *(const floatx4*)(gw + (size_t)i * NE);
      const floatx4 w01 = *(const floatx4*)(gw + (size_t)i * NE + 4);
      const floatx4 w10 = *(const floatx4*)(gw + (size_t)(i + 1) * NE);
      const floatx4 w11 = *(const floatx4*)(gw + (size_t)(i + 1) * NE + 4);
#pragma unroll
      for (int e = 0; e < 4; ++e) {
        acc[e]     += xv[0] * w00[e] + xv[1] * w10[e];
        acc[e + 4] += xv[0] * w01[e] + xv[1] * w11[e];
      }
    }
#pragma unroll
    for (int e = 0; e < NE; ++e) {
#pragma unroll
      for (int off = 32; off > 0; off >>= 1)
        acc[e] += __shfl_xor(acc[e], off, 64);
    }
    float lg[NE];
    float mx = -3.0e38f;
#pragma unroll
    for (int e = 0; e < NE; ++e) { lg[e] = acc[e] + gb[e]; mx = fmaxf(mx, lg[e]); }
    float s = 0.f;
#pragma unroll
    for (int e = 0; e < NE; ++e) { lg[e] = __expf(lg[e] - mx); s += lg[e]; }
    const float inv = 1.f / s;
    if (lane == 0) {
      floatx4 o0, o1;
#pragma unroll
      for (int e = 0; e < 4; ++e) { o0[e] = lg[e] * inv; o1[e] = lg[e + 4] * inv; }
      *(floatx4*)(g + (size_t)t * NE) = o0;
      *(floatx4*)(g + (size_t)t * NE + 4) = o1;
    }
  } else {
    // ---- W transpose: 64x64 tile per block ----
    const int b = blockIdx.x - 2048;
    const int e = b >> 8;
    const int i0 = ((b >> 4) & 15) * 64;
    const int o0 = (b & 15) * 64;
    const int tid = threadIdx.x;
    const int c4 = (tid & 15) * 4;
    const int r = tid >> 4;  // 0..15

    const float* src = w + ((size_t)e * DIN + i0) * DOUT + o0;
#pragma unroll
    for (int rr = r; rr < 64; rr += 16) {
      const floatx4 v = *(const floatx4*)(src + (size_t)rr * DOUT + c4);
      tile[rr][c4] = v[0]; tile[rr][c4 + 1] = v[1];
      tile[rr][c4 + 2] = v[2]; tile[rr][c4 + 3] = v[3];
    }
    __syncthreads();
    bf16* dst = wt + ((size_t)e * DOUT + o0) * DIN + i0;
#pragma unroll
    for (int rr = r; rr < 64; rr += 16) {
      union { bf16 b[4]; uint64_t u; } cv;
#pragma unroll
      for (int j = 0; j < 4; ++j) cv.b[j] = (bf16)tile[c4 + j][rr];
      *(uint64_t*)(dst + (size_t)rr * DIN + c4) = cv.u;
    }
  }
}

// ---------------------------------------------------------------------------
// Fused MoE GEMM. 128x128 tile, BK=32, XOR-swizzled LDS (conflict-free, R2).
// Round 3: 512 threads / 8 waves per block (wave tile 64x32 = 4x2 MFMA) so
// grid=512 gives 16 waves/CU instead of 8 — doubles barrier-drain hiding.
// Staging: exactly one async16 per thread per buffer (512 x 16B = 8KB tile).
// ---------------------------------------------------------------------------
__global__ __launch_bounds__(512, 4) void moe_gemm(
    const bf16* __restrict__ xb, const bf16* __restrict__ wt,
    const float* __restrict__ g, float* __restrict__ out) {
  __shared__ __align__(16) bf16 As[128 * 32];
  __shared__ __align__(16) bf16 Bs[128 * 32];

  const int tid = threadIdx.x;          // 0..511
  const int bm = blockIdx.x >> 3;
  const int bn = blockIdx.x & 7;
  const int lane = tid & 63;
  const int wave = tid >> 6;            // 0..7
  const int wm = wave >> 2;             // 0..1 (M 64-half)
  const int wn = wave & 3;              // 0..3 (N 32-slice)
  const int lr = lane & 15, lq = lane >> 4;

  const int srow = tid >> 2;                                // 0..127
  const int scol = (((tid & 3) ^ ((tid >> 3) & 3)) << 3);   // swizzled k-group

  const bf16* agp = xb + ((size_t)(bm * 128 + srow)) * DIN + scol;
  bf16* const alp = As + tid * 8;
  bf16* const blp = Bs + tid * 8;

  // fragment read k-offset (row bases are multiples of 16 -> phase = (lr>>1)&3)
  const int kgp = ((lq ^ ((lr >> 1) & 3)) << 3);

  const floatx4 fzero = {0.f, 0.f, 0.f, 0.f};
  floatx4 accF[4][2];
#pragma unroll
  for (int im = 0; im < 4; ++im)
#pragma unroll
    for (int in = 0; in < 2; ++in) accF[im][in] = fzero;

  const int tok0 = bm * 128 + wm * 64;

  for (int e = 0; e < NE; ++e) {
    const bf16* bgp = wt + ((size_t)e << 20) +
                      ((size_t)(bn * 128 + srow)) * DIN + scol;
    floatx4 accE[4][2];
#pragma unroll
    for (int im = 0; im < 4; ++im)
#pragma unroll
      for (int in = 0; in < 2; ++in) accE[im][in] = fzero;

    for (int k0 = 0; k0 < DIN; k0 += 32) {
      __syncthreads();
      async16(agp + k0, alp);
      async16(bgp + k0, blp);
      __syncthreads();

      bf16x8 av[4], bv[2];
#pragma unroll
      for (int im = 0; im < 4; ++im)
        av[im] = *(const bf16x8*)(As + (wm * 64 + im * 16 + lr) * 32 + kgp);
#pragma unroll
      for (int in = 0; in < 2; ++in)
        bv[in] = *(const bf16x8*)(Bs + (wn * 32 + in * 16 + lr) * 32 + kgp);
#pragma unroll
      for (int im = 0; im < 4; ++im)
#pragma unroll
        for (int in = 0; in < 2; ++in)
          accE[im][in] = __builtin_amdgcn_mfma_f32_16x16x32_bf16(
              av[im], bv[in], accE[im][in], 0, 0, 0);
    }

    // fold: accF += g[row, e] * accE   (fp32)
#pragma unroll
    for (int im = 0; im < 4; ++im) {
      float gv[4];
#pragma unroll
      for (int r = 0; r < 4; ++r)
        gv[r] = g[(size_t)(tok0 + im * 16 + lq * 4 + r) * NE + e];
#pragma unroll
      for (int in = 0; in < 2; ++in)
#pragma unroll
        for (int r = 0; r < 4; ++r)
          accF[im][in][r] += gv[r] * accE[im][in][r];
    }
  }

#pragma unroll
  for (int im = 0; im < 4; ++im)
#pragma unroll
    for (int in = 0; in < 2; ++in) {
      const int col = bn * 128 + wn * 32 + in * 16 + lr;
#pragma unroll
      for (int r = 0; r < 4; ++r)
        out[(size_t)(tok0 + im * 16 + lq * 4 + r) * DOUT + col] =
            accF[im][in][r];
    }
}

// ---------------------------------------------------------------------------
extern "C" void kernel_launch(void* const* d_in, const int* in_sizes, int n_in,
                              void* d_out, int out_size, void* d_ws,
                              size_t ws_size, hipStream_t stream) {
  const float* x  = (const float*)d_in[0];
  const float* gw = (const float*)d_in[1];
  const float* gb = (const float*)d_in[2];
  const float* w  = (const float*)d_in[3];
  float* out = (float*)d_out;

  char* ws = (char*)d_ws;
  float* g  = (float*)ws;
  bf16* xb  = (bf16*)(ws + 262144);
  bf16* wt  = (bf16*)(ws + 262144 + (size_t)TOKENS * DIN * 2);

  prep_kernel<<<4096, 256, 0, stream>>>(x, gw, gb, g, xb, w, wt);
  moe_gemm<<<512, 512, 0, stream>>>(xb, wt, g, out);
}

// Round 4
// 271.495 us; speedup vs baseline: 1.2188x; 1.2188x over previous
//
#include <hip/hip_runtime.h>
#include <hip/hip_bf16.h>
#include <cstdint>

#define TOKENS 8192
#define DIN 1024
#define DOUT 1024
#define NE 8

typedef __bf16 bf16;
typedef __attribute__((ext_vector_type(8))) __bf16 bf16x8;
typedef __attribute__((ext_vector_type(4))) float floatx4;
typedef __attribute__((ext_vector_type(2))) float floatx2;

// async global->LDS, 16B per lane. LDS dest must be wave-uniform base + lane*16.
__device__ __forceinline__ void async16(const void* gptr, void* lptr) {
  __builtin_amdgcn_global_load_lds(
      (const __attribute__((address_space(1))) void*)gptr,
      (__attribute__((address_space(3))) void*)lptr,
      16, 0, 0);
}

// ---------------------------------------------------------------------------
// Fused prep: blocks [0,2048) = gate softmax + x->bf16; blocks [2048,4096) =
// W[e][i][o] fp32 -> Wt[e][o][i] bf16 transpose.
// ---------------------------------------------------------------------------
__global__ __launch_bounds__(256) void prep_kernel(
    const float* __restrict__ x, const float* __restrict__ gw,
    const float* __restrict__ gb, float* __restrict__ g,
    bf16* __restrict__ xb, const float* __restrict__ w,
    bf16* __restrict__ wt) {
  __shared__ float tile[64][65];

  if (blockIdx.x < 2048) {
    const int lane = threadIdx.x & 63;
    const int wave = threadIdx.x >> 6;
    const int t = blockIdx.x * 4 + wave;
    const float* xr = x + (size_t)t * DIN;
    bf16* xbr = xb + (size_t)t * DIN;

    float acc[NE];
#pragma unroll
    for (int e = 0; e < NE; ++e) acc[e] = 0.f;

#pragma unroll
    for (int it = 0; it < 8; ++it) {
      const int i = it * 128 + lane * 2;
      const floatx2 xv = *(const floatx2*)(xr + i);
      union { bf16 b[2]; uint32_t u; } cv;
      cv.b[0] = (bf16)xv[0]; cv.b[1] = (bf16)xv[1];
      *(uint32_t*)(xbr + i) = cv.u;
      const floatx4 w00 = *(const floatx4*)(gw + (size_t)i * NE);
      const floatx4 w01 = *(const floatx4*)(gw + (size_t)i * NE + 4);
      const floatx4 w10 = *(const floatx4*)(gw + (size_t)(i + 1) * NE);
      const floatx4 w11 = *(const floatx4*)(gw + (size_t)(i + 1) * NE + 4);
#pragma unroll
      for (int e = 0; e < 4; ++e) {
        acc[e]     += xv[0] * w00[e] + xv[1] * w10[e];
        acc[e + 4] += xv[0] * w01[e] + xv[1] * w11[e];
      }
    }
#pragma unroll
    for (int e = 0; e < NE; ++e) {
#pragma unroll
      for (int off = 32; off > 0; off >>= 1)
        acc[e] += __shfl_xor(acc[e], off, 64);
    }
    float lg[NE];
    float mx = -3.0e38f;
#pragma unroll
    for (int e = 0; e < NE; ++e) { lg[e] = acc[e] + gb[e]; mx = fmaxf(mx, lg[e]); }
    float s = 0.f;
#pragma unroll
    for (int e = 0; e < NE; ++e) { lg[e] = __expf(lg[e] - mx); s += lg[e]; }
    const float inv = 1.f / s;
    if (lane == 0) {
      floatx4 o0, o1;
#pragma unroll
      for (int e = 0; e < 4; ++e) { o0[e] = lg[e] * inv; o1[e] = lg[e + 4] * inv; }
      *(floatx4*)(g + (size_t)t * NE) = o0;
      *(floatx4*)(g + (size_t)t * NE + 4) = o1;
    }
  } else {
    const int b = blockIdx.x - 2048;
    const int e = b >> 8;
    const int i0 = ((b >> 4) & 15) * 64;
    const int o0 = (b & 15) * 64;
    const int tid = threadIdx.x;
    const int c4 = (tid & 15) * 4;
    const int r = tid >> 4;

    const float* src = w + ((size_t)e * DIN + i0) * DOUT + o0;
#pragma unroll
    for (int rr = r; rr < 64; rr += 16) {
      const floatx4 v = *(const floatx4*)(src + (size_t)rr * DOUT + c4);
      tile[rr][c4] = v[0]; tile[rr][c4 + 1] = v[1];
      tile[rr][c4 + 2] = v[2]; tile[rr][c4 + 3] = v[3];
    }
    __syncthreads();
    bf16* dst = wt + ((size_t)e * DOUT + o0) * DIN + i0;
#pragma unroll
    for (int rr = r; rr < 64; rr += 16) {
      union { bf16 b[4]; uint64_t u; } cv;
#pragma unroll
      for (int j = 0; j < 4; ++j) cv.b[j] = (bf16)tile[c4 + j][rr];
      *(uint64_t*)(dst + (size_t)rr * DIN + c4) = cv.u;
    }
  }
}

// ---------------------------------------------------------------------------
// Fused MoE GEMM. R4: 256 threads / 4 waves (64x64 wave tile, as R2) with
// BK=64 — 32 MFMA per wave per barrier (2x R2), 16 barriers per expert.
// LDS 2 x 16KB. XOR swizzle for 8 units/row: phys unit = row*8+(kg^(row&7));
// read group = (h*4+lq)^(lr&7) covers all 8 groups over 8 lanes (2-way=free);
// staging permutes global cols only within a row's 128B span (coalesced),
// LDS dest = tid*16 + j*4096 (wave-uniform base + lane*16, legal).
// ---------------------------------------------------------------------------
__global__ __launch_bounds__(256, 2) void moe_gemm(
    const bf16* __restrict__ xb, const bf16* __restrict__ wt,
    const float* __restrict__ g, float* __restrict__ out) {
  __shared__ __align__(16) bf16 As[128 * 64];  // 16KB
  __shared__ __align__(16) bf16 Bs[128 * 64];  // 16KB

  const int tid = threadIdx.x;
  const int bm = blockIdx.x >> 3;
  const int bn = blockIdx.x & 7;
  const int lane = tid & 63;
  const int wave = tid >> 6;
  const int wm = wave >> 1, wn = wave & 1;
  const int lr = lane & 15, lq = lane >> 4;

  // staging: thread tid covers phys units {tid + 256j}, j=0..3 per buffer.
  // unit u -> row = u>>3 (row0 + 32j), pkg = u&7, global col = (pkg^(row&7))*8
  // (row&7 invariant across j since 32j === 0 mod 8).
  const int srow = tid >> 3;                                  // 0..31
  const int scol = (((tid & 7) ^ (srow & 7)) << 3);           // swizzled col

  const bf16* agp = xb + ((size_t)(bm * 128 + srow)) * DIN + scol;
  bf16* const alp = As + tid * 8;
  bf16* const blp = Bs + tid * 8;

  // fragment read: elem offset = row*64 + ((h*4+lq)^(lr&7))*8, row base mult 16
  const int kx = lr & 7;

  const floatx4 fzero = {0.f, 0.f, 0.f, 0.f};
  floatx4 accF[4][4];
#pragma unroll
  for (int im = 0; im < 4; ++im)
#pragma unroll
    for (int in = 0; in < 4; ++in) accF[im][in] = fzero;

  const int tok0 = bm * 128 + wm * 64;

  for (int e = 0; e < NE; ++e) {
    const bf16* bgp = wt + ((size_t)e << 20) +
                      ((size_t)(bn * 128 + srow)) * DIN + scol;
    floatx4 accE[4][4];
#pragma unroll
    for (int im = 0; im < 4; ++im)
#pragma unroll
      for (int in = 0; in < 4; ++in) accE[im][in] = fzero;

    for (int k0 = 0; k0 < DIN; k0 += 64) {
      __syncthreads();
#pragma unroll
      for (int j = 0; j < 4; ++j) {
        async16(agp + k0 + (size_t)(32 * j) * DIN, alp + j * 2048);
        async16(bgp + k0 + (size_t)(32 * j) * DIN, blp + j * 2048);
      }
      __syncthreads();

#pragma unroll
      for (int h = 0; h < 2; ++h) {
        const int kg = ((h * 4 + lq) ^ kx) << 3;
        bf16x8 av[4], bv[4];
#pragma unroll
        for (int im = 0; im < 4; ++im)
          av[im] = *(const bf16x8*)(As + (wm * 64 + im * 16 + lr) * 64 + kg);
#pragma unroll
        for (int in = 0; in < 4; ++in)
          bv[in] = *(const bf16x8*)(Bs + (wn * 64 + in * 16 + lr) * 64 + kg);
#pragma unroll
        for (int im = 0; im < 4; ++im)
#pragma unroll
          for (int in = 0; in < 4; ++in)
            accE[im][in] = __builtin_amdgcn_mfma_f32_16x16x32_bf16(
                av[im], bv[in], accE[im][in], 0, 0, 0);
      }
    }

    // fold: accF += g[row, e] * accE
#pragma unroll
    for (int im = 0; im < 4; ++im) {
      float gv[4];
#pragma unroll
      for (int r = 0; r < 4; ++r)
        gv[r] = g[(size_t)(tok0 + im * 16 + lq * 4 + r) * NE + e];
#pragma unroll
      for (int in = 0; in < 4; ++in)
#pragma unroll
        for (int r = 0; r < 4; ++r)
          accF[im][in][r] += gv[r] * accE[im][in][r];
    }
  }

#pragma unroll
  for (int im = 0; im < 4; ++im)
#pragma unroll
    for (int in = 0; in < 4; ++in) {
      const int col = bn * 128 + wn * 64 + in * 16 + lr;
#pragma unroll
      for (int r = 0; r < 4; ++r)
        out[(size_t)(tok0 + im * 16 + lq * 4 + r) * DOUT + col] =
            accF[im][in][r];
    }
}

// ---------------------------------------------------------------------------
extern "C" void kernel_launch(void* const* d_in, const int* in_sizes, int n_in,
                              void* d_out, int out_size, void* d_ws,
                              size_t ws_size, hipStream_t stream) {
  const float* x  = (const float*)d_in[0];
  const float* gw = (const float*)d_in[1];
  const float* gb = (const float*)d_in[2];
  const float* w  = (const float*)d_in[3];
  float* out = (float*)d_out;

  char* ws = (char*)d_ws;
  float* g  = (float*)ws;
  bf16* xb  = (bf16*)(ws + 262144);
  bf16* wt  = (bf16*)(ws + 262144 + (size_t)TOKENS * DIN * 2);

  prep_kernel<<<4096, 256, 0, stream>>>(x, gw, gb, g, xb, w, wt);
  moe_gemm<<<512, 256, 0, stream>>>(xb, wt, g, out);
}

// Round 6
// 268.166 us; speedup vs baseline: 1.2339x; 1.0124x over previous
//
#include <hip/hip_runtime.h>
#include <hip/hip_bf16.h>
#include <cstdint>

#define TOKENS 8192
#define DIN 1024
#define DOUT 1024
#define NE 8

typedef __bf16 bf16;
typedef __attribute__((ext_vector_type(8))) __bf16 bf16x8;
typedef __attribute__((ext_vector_type(4))) float floatx4;
typedef __attribute__((ext_vector_type(2))) float floatx2;

// async global->LDS, 16B per lane. LDS dest must be wave-uniform base + lane*16.
__device__ __forceinline__ void async16(const void* gptr, void* lptr) {
  __builtin_amdgcn_global_load_lds(
      (const __attribute__((address_space(1))) void*)gptr,
      (__attribute__((address_space(3))) void*)lptr,
      16, 0, 0);
}

// ---------------------------------------------------------------------------
// Fused prep: blocks [0,2048) = gate softmax + x->bf16; blocks [2048,4096) =
// W[e][i][o] fp32 -> Wt[e][o][i] bf16 transpose.
// ---------------------------------------------------------------------------
__global__ __launch_bounds__(256) void prep_kernel(
    const float* __restrict__ x, const float* __restrict__ gw,
    const float* __restrict__ gb, float* __restrict__ g,
    bf16* __restrict__ xb, const float* __restrict__ w,
    bf16* __restrict__ wt) {
  __shared__ float tile[64][65];

  if (blockIdx.x < 2048) {
    const int lane = threadIdx.x & 63;
    const int wave = threadIdx.x >> 6;
    const int t = blockIdx.x * 4 + wave;
    const float* xr = x + (size_t)t * DIN;
    bf16* xbr = xb + (size_t)t * DIN;

    float acc[NE];
#pragma unroll
    for (int e = 0; e < NE; ++e) acc[e] = 0.f;

#pragma unroll
    for (int it = 0; it < 8; ++it) {
      const int i = it * 128 + lane * 2;
      const floatx2 xv = *(const floatx2*)(xr + i);
      union { bf16 b[2]; uint32_t u; } cv;
      cv.b[0] = (bf16)xv[0]; cv.b[1] = (bf16)xv[1];
      *(uint32_t*)(xbr + i) = cv.u;
      const floatx4 w00 = *(const floatx4*)(gw + (size_t)i * NE);
      const floatx4 w01 = *(const floatx4*)(gw + (size_t)i * NE + 4);
      const floatx4 w10 = *(const floatx4*)(gw + (size_t)(i + 1) * NE);
      const floatx4 w11 = *(const floatx4*)(gw + (size_t)(i + 1) * NE + 4);
#pragma unroll
      for (int e = 0; e < 4; ++e) {
        acc[e]     += xv[0] * w00[e] + xv[1] * w10[e];
        acc[e + 4] += xv[0] * w01[e] + xv[1] * w11[e];
      }
    }
#pragma unroll
    for (int e = 0; e < NE; ++e) {
#pragma unroll
      for (int off = 32; off > 0; off >>= 1)
        acc[e] += __shfl_xor(acc[e], off, 64);
    }
    float lg[NE];
    float mx = -3.0e38f;
#pragma unroll
    for (int e = 0; e < NE; ++e) { lg[e] = acc[e] + gb[e]; mx = fmaxf(mx, lg[e]); }
    float s = 0.f;
#pragma unroll
    for (int e = 0; e < NE; ++e) { lg[e] = __expf(lg[e] - mx); s += lg[e]; }
    const float inv = 1.f / s;
    if (lane == 0) {
      floatx4 o0, o1;
#pragma unroll
      for (int e = 0; e < 4; ++e) { o0[e] = lg[e] * inv; o1[e] = lg[e + 4] * inv; }
      *(floatx4*)(g + (size_t)t * NE) = o0;
      *(floatx4*)(g + (size_t)t * NE + 4) = o1;
    }
  } else {
    const int b = blockIdx.x - 2048;
    const int e = b >> 8;
    const int i0 = ((b >> 4) & 15) * 64;
    const int o0 = (b & 15) * 64;
    const int tid = threadIdx.x;
    const int c4 = (tid & 15) * 4;
    const int r = tid >> 4;

    const float* src = w + ((size_t)e * DIN + i0) * DOUT + o0;
#pragma unroll
    for (int rr = r; rr < 64; rr += 16) {
      const floatx4 v = *(const floatx4*)(src + (size_t)rr * DOUT + c4);
      tile[rr][c4] = v[0]; tile[rr][c4 + 1] = v[1];
      tile[rr][c4 + 2] = v[2]; tile[rr][c4 + 3] = v[3];
    }
    __syncthreads();
    bf16* dst = wt + ((size_t)e * DOUT + o0) * DIN + i0;
#pragma unroll
    for (int rr = r; rr < 64; rr += 16) {
      union { bf16 b[4]; uint64_t u; } cv;
#pragma unroll
      for (int j = 0; j < 4; ++j) cv.b[j] = (bf16)tile[c4 + j][rr];
      *(uint64_t*)(dst + (size_t)rr * DIN + c4) = cv.u;
    }
  }
}

// ---------------------------------------------------------------------------
// Fused MoE GEMM. R6 = R5 with the staging-offset bug fixed: each pass of
// 256 threads x 16B covers 4096 BYTES, so pass j lands at element j*2048
// (R5 wrongly used j*4096 elements -> LDS OOB -> NaN).
// BK=128: 64 MFMA per wave per barrier, 8 barrier windows per expert.
// LDS 2 x 32KB = 64KB/block (128KB/CU at the 2-blocks/CU cap from grid+regs).
// Swizzle, 16 units/row: phys pos = kg ^ (row&7); read phase lanes 0..15
// sweep all 8 bank groups twice (2-way = free, same as R2/R4 measured 0).
// ---------------------------------------------------------------------------
__global__ __launch_bounds__(256, 2) void moe_gemm(
    const bf16* __restrict__ xb, const bf16* __restrict__ wt,
    const float* __restrict__ g, float* __restrict__ out) {
  __shared__ __align__(16) bf16 As[128 * 128];  // 32KB
  __shared__ __align__(16) bf16 Bs[128 * 128];  // 32KB

  const int tid = threadIdx.x;
  const int bm = blockIdx.x >> 3;
  const int bn = blockIdx.x & 7;
  const int lane = tid & 63;
  const int wave = tid >> 6;
  const int wm = wave >> 1, wn = wave & 1;
  const int lr = lane & 15, lq = lane >> 4;

  // staging: pass j writes 16B-units {tid + 256j}; unit u -> row = u>>4
  // (= srow + 16j), pos = u&15, global col = (pos ^ (row&7))*8; row&7
  // invariant across j (16j === 0 mod 8).
  const int srow = tid >> 4;                                  // 0..15
  const int scol = (((tid & 15) ^ (srow & 7)) << 3);          // swizzled col

  const bf16* agp = xb + ((size_t)(bm * 128 + srow)) * DIN + scol;
  bf16* const alp = As + tid * 8;
  bf16* const blp = Bs + tid * 8;

  // fragment read: elem offset = row*128 + ((h*4+lq)^(lr&7))*8
  const int kx = lr & 7;

  const floatx4 fzero = {0.f, 0.f, 0.f, 0.f};
  floatx4 accF[4][4];
#pragma unroll
  for (int im = 0; im < 4; ++im)
#pragma unroll
    for (int in = 0; in < 4; ++in) accF[im][in] = fzero;

  const int tok0 = bm * 128 + wm * 64;

  for (int e = 0; e < NE; ++e) {
    const bf16* bgp = wt + ((size_t)e << 20) +
                      ((size_t)(bn * 128 + srow)) * DIN + scol;
    floatx4 accE[4][4];
#pragma unroll
    for (int im = 0; im < 4; ++im)
#pragma unroll
      for (int in = 0; in < 4; ++in) accE[im][in] = fzero;

    for (int k0 = 0; k0 < DIN; k0 += 128) {
      __syncthreads();
#pragma unroll
      for (int j = 0; j < 8; ++j) {
        // pass j: byte offset j*4096 = element offset j*2048 (FIXED)
        async16(agp + k0 + (size_t)(16 * j) * DIN, alp + j * 2048);
        async16(bgp + k0 + (size_t)(16 * j) * DIN, blp + j * 2048);
      }
      __syncthreads();

#pragma unroll
      for (int h = 0; h < 4; ++h) {
        const int kg = ((h * 4 + lq) ^ kx) << 3;
        bf16x8 av[4], bv[4];
#pragma unroll
        for (int im = 0; im < 4; ++im)
          av[im] = *(const bf16x8*)(As + (wm * 64 + im * 16 + lr) * 128 + kg);
#pragma unroll
        for (int in = 0; in < 4; ++in)
          bv[in] = *(const bf16x8*)(Bs + (wn * 64 + in * 16 + lr) * 128 + kg);
#pragma unroll
        for (int im = 0; im < 4; ++im)
#pragma unroll
          for (int in = 0; in < 4; ++in)
            accE[im][in] = __builtin_amdgcn_mfma_f32_16x16x32_bf16(
                av[im], bv[in], accE[im][in], 0, 0, 0);
      }
    }

    // fold: accF += g[row, e] * accE
#pragma unroll
    for (int im = 0; im < 4; ++im) {
      float gv[4];
#pragma unroll
      for (int r = 0; r < 4; ++r)
        gv[r] = g[(size_t)(tok0 + im * 16 + lq * 4 + r) * NE + e];
#pragma unroll
      for (int in = 0; in < 4; ++in)
#pragma unroll
        for (int r = 0; r < 4; ++r)
          accF[im][in][r] += gv[r] * accE[im][in][r];
    }
  }

#pragma unroll
  for (int im = 0; im < 4; ++im)
#pragma unroll
    for (int in = 0; in < 4; ++in) {
      const int col = bn * 128 + wn * 64 + in * 16 + lr;
#pragma unroll
      for (int r = 0; r < 4; ++r)
        out[(size_t)(tok0 + im * 16 + lq * 4 + r) * DOUT + col] =
            accF[im][in][r];
    }
}

// ---------------------------------------------------------------------------
extern "C" void kernel_launch(void* const* d_in, const int* in_sizes, int n_in,
                              void* d_out, int out_size, void* d_ws,
                              size_t ws_size, hipStream_t stream) {
  const float* x  = (const float*)d_in[0];
  const float* gw = (const float*)d_in[1];
  const float* gb = (const float*)d_in[2];
  const float* w  = (const float*)d_in[3];
  float* out = (float*)d_out;

  char* ws = (char*)d_ws;
  float* g  = (float*)ws;
  bf16* xb  = (bf16*)(ws + 262144);
  bf16* wt  = (bf16*)(ws + 262144 + (size_t)TOKENS * DIN * 2);

  prep_kernel<<<4096, 256, 0, stream>>>(x, gw, gb, g, xb, w, wt);
  moe_gemm<<<512, 256, 0, stream>>>(xb, wt, g, out);
}